// Round 6
// baseline (316.558 us; speedup 1.0000x reference)
//
#include <hip/hip_runtime.h>

// upfirdn2d: up=2, 4x4 depthwise FIR, pad (2,2), no downsample.
// x: (16,64,128,128) f32, filt: (64,1,4,4) f32, out: (16,64,256,256) f32.
//
// Polyphase (correlation, XLA semantics):
//   out row 2i   = K[0][.]*row(i-1) + K[2][.]*row(i)
//   out row 2i+1 = K[1][.]*row(i)   + K[3][.]*row(i+1)
//   out col 2jj   = K[.][0]*col(jj-1) + K[.][2]*col(jj)
//   out col 2jj+1 = K[.][1]*col(jj)   + K[.][3]*col(jj+1)
// Out-of-range input == 0 (zero padding).
//
// One wave (64 lanes) spans a full 128-col input row; horizontal halo via
// __shfl. Each thread produces 8 output rows x 4 cols from 6 input rows
// (rows 4q-1 .. 4q+4). Plain stores (match the 6.5 TB/s fill pattern).

constexpr int H = 128, W = 128, WO = 256;

typedef float vfloat4 __attribute__((ext_vector_type(4)));

__global__ __launch_bounds__(256) void upfirdn2d_up2(
    const float* __restrict__ x, const float* __restrict__ f,
    float* __restrict__ y) {
  const int j  = threadIdx.x;                  // 0..63 -> output cols 4j..4j+3
  const int q  = blockIdx.x * 4 + threadIdx.y; // 0..31 -> output rows 8q..8q+7
  const int bc = blockIdx.y;                   // 0..1023 (b*64 + c)
  const int c  = bc & 63;

  // 16 filter taps; uniform per block -> scalar loads / SGPRs.
  float k[16];
  const float* kp = f + c * 16;
#pragma unroll
  for (int t = 0; t < 16; ++t) k[t] = kp[t];

  const float* xin = x + (size_t)bc * (H * W);
  float*       yo  = y + (size_t)bc * (WO * WO);

  // Input rows 4q-1 .. 4q+4; per row, cols 2j-1, 2j, 2j+1, 2j+2.
  float a[6][4];
#pragma unroll
  for (int t = 0; t < 6; ++t) {
    const int row = 4 * q - 1 + t;
    const bool rok = ((unsigned)row < (unsigned)H);
    float2 mid = rok ? *(const float2*)(xin + row * W + 2 * j)
                     : make_float2(0.f, 0.f);
    const float left  = __shfl_up(mid.y, 1);   // lane j-1's col 2j-1
    const float right = __shfl_down(mid.x, 1); // lane j+1's col 2j+2
    a[t][0] = (j == 0)  ? 0.f : left;
    a[t][1] = mid.x;
    a[t][2] = mid.y;
    a[t][3] = (j == 63) ? 0.f : right;
  }

  // kr = filter row for the upper input row, ks = for the lower input row.
  auto frow = [&](const float* kr, const float (&u)[4],
                  const float* ks, const float (&v)[4]) -> vfloat4 {
    vfloat4 o;
    o.x = kr[0]*u[0] + kr[2]*u[1] + ks[0]*v[0] + ks[2]*v[1];
    o.y = kr[1]*u[1] + kr[3]*u[2] + ks[1]*v[1] + ks[3]*v[2];
    o.z = kr[0]*u[1] + kr[2]*u[2] + ks[0]*v[1] + ks[2]*v[2];
    o.w = kr[1]*u[2] + kr[3]*u[3] + ks[1]*v[2] + ks[3]*v[3];
    return o;
  };

  float* base = yo + (size_t)(8 * q) * WO + 4 * j;
#pragma unroll
  for (int s = 0; s < 4; ++s) {
    // out row 8q+2s   (i = 4q+s): K rows 0,2 on input rows i-1, i
    // out row 8q+2s+1           : K rows 1,3 on input rows i, i+1
    const vfloat4 oe = frow(k + 0, a[s],     k + 8,  a[s + 1]);
    const vfloat4 oo = frow(k + 4, a[s + 1], k + 12, a[s + 2]);
    *(vfloat4*)(base + (size_t)(2 * s)     * WO) = oe;
    *(vfloat4*)(base + (size_t)(2 * s + 1) * WO) = oo;
  }
}

extern "C" void kernel_launch(void* const* d_in, const int* in_sizes, int n_in,
                              void* d_out, int out_size, void* d_ws, size_t ws_size,
                              hipStream_t stream) {
  const float* x = (const float*)d_in[0];
  const float* f = (const float*)d_in[1];
  float*       y = (float*)d_out;

  dim3 block(64, 4);  // one wave per 8-output-row strip; 4 strips per block
  dim3 grid(8, 1024); // 8*4 = 32 strips = 256 output rows; 1024 (b,c) planes
  hipLaunchKernelGGL(upfirdn2d_up2, grid, block, 0, stream, x, f, y);
}

// Round 7
// 309.873 us; speedup vs baseline: 1.0216x; 1.0216x over previous
//
#include <hip/hip_runtime.h>

// upfirdn2d: up=2, 4x4 depthwise FIR, pad (2,2), no downsample.
// x: (16,64,128,128) f32, filt: (64,1,4,4) f32, out: (16,64,256,256) f32.
//
// Polyphase (correlation, XLA semantics):
//   out row 2i   = K[0][.]*row(i-1) + K[2][.]*row(i)
//   out row 2i+1 = K[1][.]*row(i)   + K[3][.]*row(i+1)
//   out col 2jj   = K[.][0]*col(jj-1) + K[.][2]*col(jj)
//   out col 2jj+1 = K[.][1]*col(jj)   + K[.][3]*col(jj+1)
// Out-of-range input == 0 (zero padding).
//
// One wave (64 lanes) spans a full 128-col input row; horizontal halo via
// __shfl. Each thread produces 8 output rows x 4 cols from 6 input rows
// (rows 4q-1 .. 4q+4). NT stores: keep the 256 MiB write-once stream out of
// L2/L3 so input halo re-reads stay cache-resident (R5=306us w/ NT vs
// R6=316.6us w/ plain stores — this round bisects store type vs strip size).

constexpr int H = 128, W = 128, WO = 256;

typedef float vfloat4 __attribute__((ext_vector_type(4)));

__global__ __launch_bounds__(256) void upfirdn2d_up2(
    const float* __restrict__ x, const float* __restrict__ f,
    float* __restrict__ y) {
  const int j  = threadIdx.x;                  // 0..63 -> output cols 4j..4j+3
  const int q  = blockIdx.x * 4 + threadIdx.y; // 0..31 -> output rows 8q..8q+7
  const int bc = blockIdx.y;                   // 0..1023 (b*64 + c)
  const int c  = bc & 63;

  // 16 filter taps; uniform per block -> scalar loads / SGPRs.
  float k[16];
  const float* kp = f + c * 16;
#pragma unroll
  for (int t = 0; t < 16; ++t) k[t] = kp[t];

  const float* xin = x + (size_t)bc * (H * W);
  float*       yo  = y + (size_t)bc * (WO * WO);

  // Input rows 4q-1 .. 4q+4; per row, cols 2j-1, 2j, 2j+1, 2j+2.
  float a[6][4];
#pragma unroll
  for (int t = 0; t < 6; ++t) {
    const int row = 4 * q - 1 + t;
    const bool rok = ((unsigned)row < (unsigned)H);
    float2 mid = rok ? *(const float2*)(xin + row * W + 2 * j)
                     : make_float2(0.f, 0.f);
    const float left  = __shfl_up(mid.y, 1);   // lane j-1's col 2j-1
    const float right = __shfl_down(mid.x, 1); // lane j+1's col 2j+2
    a[t][0] = (j == 0)  ? 0.f : left;
    a[t][1] = mid.x;
    a[t][2] = mid.y;
    a[t][3] = (j == 63) ? 0.f : right;
  }

  // kr = filter row for the upper input row, ks = for the lower input row.
  auto frow = [&](const float* kr, const float (&u)[4],
                  const float* ks, const float (&v)[4]) -> vfloat4 {
    vfloat4 o;
    o.x = kr[0]*u[0] + kr[2]*u[1] + ks[0]*v[0] + ks[2]*v[1];
    o.y = kr[1]*u[1] + kr[3]*u[2] + ks[1]*v[1] + ks[3]*v[2];
    o.z = kr[0]*u[1] + kr[2]*u[2] + ks[0]*v[1] + ks[2]*v[2];
    o.w = kr[1]*u[2] + kr[3]*u[3] + ks[1]*v[2] + ks[3]*v[3];
    return o;
  };

  float* base = yo + (size_t)(8 * q) * WO + 4 * j;
#pragma unroll
  for (int s = 0; s < 4; ++s) {
    // out row 8q+2s   (i = 4q+s): K rows 0,2 on input rows i-1, i
    // out row 8q+2s+1           : K rows 1,3 on input rows i, i+1
    const vfloat4 oe = frow(k + 0, a[s],     k + 8,  a[s + 1]);
    const vfloat4 oo = frow(k + 4, a[s + 1], k + 12, a[s + 2]);
    __builtin_nontemporal_store(oe, (vfloat4*)(base + (size_t)(2 * s)     * WO));
    __builtin_nontemporal_store(oo, (vfloat4*)(base + (size_t)(2 * s + 1) * WO));
  }
}

extern "C" void kernel_launch(void* const* d_in, const int* in_sizes, int n_in,
                              void* d_out, int out_size, void* d_ws, size_t ws_size,
                              hipStream_t stream) {
  const float* x = (const float*)d_in[0];
  const float* f = (const float*)d_in[1];
  float*       y = (float*)d_out;

  dim3 block(64, 4);  // one wave per 8-output-row strip; 4 strips per block
  dim3 grid(8, 1024); // 8*4 = 32 strips = 256 output rows; 1024 (b,c) planes
  hipLaunchKernelGGL(upfirdn2d_up2, grid, block, 0, stream, x, f, y);
}